// Round 2
// baseline (637.127 us; speedup 1.0000x reference)
//
#include <hip/hip_runtime.h>
#include <stdint.h>

// Problem constants
#define T_STEPS 512
#define HID     64
#define INP     10
#define MB      16          // samples per block
#define KS      88          // k-stride (elements) of packed W layout [t][n][KS]
#define HS      72          // h LDS row stride (elems) : 144B, 16B-aligned, 2-way banks (free)
#define XS      40          // x LDS row stride (elems) : 80B, 16B-aligned, 2-way banks (free)
#define WT_ELEMS (HID*KS)       // 5632 bf16 per step (global packed tile)
#define WT_BYTES (WT_ELEMS*2)   // 11264 B per step
#define WS_SLOTS (WT_BYTES/16)  // 704 16B slots of real data
#define WB_SLOTS 768            // padded to 3*256 -> uniform 3 loads/thread (vmcnt counting)
#define WB_ELEMS (WB_SLOTS*8)   // 6144 shorts per LDS W buffer

typedef float  f32x4  __attribute__((ext_vector_type(4)));
typedef short  s16x8  __attribute__((ext_vector_type(8)));
typedef __bf16 bf16x8 __attribute__((ext_vector_type(8)));

typedef const __attribute__((address_space(1))) unsigned int* gp_t;
typedef __attribute__((address_space(3))) unsigned int*       lp_t;

__device__ __forceinline__ short f2bf(float f) {          // manual RNE (prep pass)
    unsigned u = __builtin_bit_cast(unsigned, f);
    u = (u + 0x7FFFu + ((u >> 16) & 1u)) >> 16;
    return (short)u;
}
__device__ __forceinline__ short f2bfh(float f) {         // hw cvt (hot loop)
    return __builtin_bit_cast(short, (__bf16)f);
}
__device__ __forceinline__ float bf2f(short s) {
    unsigned u = ((unsigned)(unsigned short)s) << 16;
    return __builtin_bit_cast(float, u);
}

// ---------------------------------------------------------------------------
// Pre-pass: pack [W_hh[t] (64x64) ; W_xh[t] (10x64) ; zeros] transposed into
// bf16 Wc[t][n][k], k-stride 88. LDS tiles padded to stride 65 so the
// transpose read s_hh[k*65+n] is bank-conflict-free.
// ---------------------------------------------------------------------------
__global__ __launch_bounds__(256) void prep_w(const float* __restrict__ Wxh,
                                              const float* __restrict__ Whh,
                                              short* __restrict__ Wc) {
    __shared__ float s_hh[64 * 65];
    __shared__ float s_xh[INP * 65];
    const int t = blockIdx.x, tid = threadIdx.x;
    for (int i = tid; i < 64 * 64; i += 256)
        s_hh[(i >> 6) * 65 + (i & 63)] = Whh[t * 4096 + i];
    for (int i = tid; i < INP * 64; i += 256)
        s_xh[(i >> 6) * 65 + (i & 63)] = Wxh[t * (INP * 64) + i];
    __syncthreads();
    short* dst = Wc + (size_t)t * WT_ELEMS;
    for (int i = tid; i < WT_ELEMS; i += 256) {
        const int n = i / KS, k = i % KS;
        float v = 0.f;
        if (k < 64)      v = s_hh[k * 65 + n];
        else if (k < 74) v = s_xh[(k - 64) * 65 + n];
        dst[i] = f2bf(v);
    }
}

// ---------------------------------------------------------------------------
// Main recurrence. 512 blocks x 256 threads, MB=16 samples/block.
// Counted-vmcnt pipeline, ALL VMEM = global_load_lds (no register dests ->
// no in-flight-register race, the round-1 nondeterminism source).
// Per wave per step exactly 4 DMA instrs: 3x W[t+2] + 1x xf32[t+3]
// (x redundantly issued by all 4 waves: identical src+dest, benign).
// Queue invariant at step entry: [W(t+1) x3, xf(t+2)] = 4 outstanding.
// One s_waitcnt vmcnt(4) + lgkmcnt(0) + raw s_barrier per step -- the next
// tiles' loads stay in flight across the barrier.
// ---------------------------------------------------------------------------
__global__ __launch_bounds__(256, 2) void rnn_main(const float* __restrict__ X,
                                                   const int* __restrict__ L,
                                                   const short* __restrict__ Wc,
                                                   const float* __restrict__ Wlin,
                                                   const float* __restrict__ blin,
                                                   float* __restrict__ out) {
    __shared__ __attribute__((aligned(16))) short Wb[3][WB_ELEMS];   // 36864 B
    __shared__ __attribute__((aligned(16))) short hb[2][MB * HS];    //  4608 B
    __shared__ __attribute__((aligned(16))) short xb[2][MB * XS];    //  2560 B
    __shared__ __attribute__((aligned(16))) float xf[4][256];        //  4096 B
    __shared__ int len_s[MB];

    const int tid  = threadIdx.x;
    const int lane = tid & 63;
    const int wv   = tid >> 6;        // wave id 0..3 -> N-tile
    const int q    = lane >> 4;       // lane quad
    const int l    = lane & 15;
    const long long bbase = (long long)blockIdx.x * MB;

    // ---- W DMA: 3 slots/thread, loop-invariant offsets; slot>=704 clamps
    // src to slot 0 (junk lands in unread LDS tail 5632..6143, finite,
    // multiplied only by guaranteed-zero A elements).
    const int ws2_src = (((tid + 512) < WS_SLOTS) ? (tid + 512) : 0) * 16;
    auto issue_w = [&](int tp, int buf) {
        const char* src = (const char*)Wc + (size_t)tp * WT_BYTES;
        char* dst = (char*)&Wb[buf][0];
        __builtin_amdgcn_global_load_lds((gp_t)(src + tid * 16),
                                         (lp_t)(dst + tid * 16), 16, 0, 0);
        __builtin_amdgcn_global_load_lds((gp_t)(src + (tid + 256) * 16),
                                         (lp_t)(dst + (tid + 256) * 16), 16, 0, 0);
        __builtin_amdgcn_global_load_lds((gp_t)(src + ws2_src),
                                         (lp_t)(dst + (tid + 512) * 16), 16, 0, 0);
    };

    // ---- x DMA: fp32 rows (40 B) covered by 3 overlapping 16B reads at row
    // offsets {0,8,24} -> 48 real slots, NEVER crosses a row (no OOB).
    // One instruction per wave (64 slots, tail clamped to slot 47).
    const int s47   = (lane < 48) ? lane : 47;
    const int xrow  = s47 / 3;
    const int xpart = s47 - xrow * 3;
    const int xpoff = (xpart == 0) ? 0 : ((xpart == 1) ? 8 : 24);
    const char* xsrc0 = (const char*)X + (size_t)(bbase + xrow) * (T_STEPS * INP * 4) + xpoff;
    auto issue_xf = [&](int tx, int buf) {
        __builtin_amdgcn_global_load_lds((gp_t)(xsrc0 + (size_t)tx * (INP * 4)),
                                         (lp_t)((char*)&xf[buf][0] + lane * 16), 16, 0, 0);
    };

    // reader mapping for the scrambled xf layout (thread -> sample xs, elem xi)
    const int xs = tid / INP, xi = tid % INP;          // valid when tid < 160
    const int xfoff = xs * 48 + xi * 4 + (xi < 4 ? 0 : 8);   // byte offset

    // ---- prologue ----------------------------------------------------------
    if (tid < MB) len_s[tid] = L[bbase + tid];
    for (int i = tid; i < MB * HS; i += 256) hb[0][i] = 0;
    for (int i = tid; i < MB * XS; i += 256) { xb[0][i] = 0; xb[1][i] = 0; }

    issue_w(0, 0);      // 3
    issue_xf(0, 0);     // 1
    issue_xf(1, 1);     // 1
    issue_w(1, 1);      // 3
    issue_xf(2, 2);     // 1   queue = 9
    asm volatile("s_waitcnt vmcnt(4)" ::: "memory");   // completes W0x3,xf0,xf1
    __builtin_amdgcn_sched_barrier(0);                 // xf0 read must stay below
    if (tid < MB * INP) {
        const float x0 = *(const float*)((const char*)&xf[0][0] + xfoff);
        xb[0][xs * XS + xi] = f2bfh(x0);
    }
    asm volatile("s_waitcnt lgkmcnt(0)" ::: "memory");
    __builtin_amdgcn_s_barrier();
    // loop-entry invariant: outstanding = [W1 x3, xf2] = 4.

    float hc[4] = {0.f, 0.f, 0.f, 0.f};
    int len4[4];
#pragma unroll
    for (int r = 0; r < 4; ++r) len4[r] = len_s[q * 4 + r];
    const int colw = wv * 16 + l;
    const int woff = colw * KS + q * 8;

    int rb = 0;   // W read-buffer index = t % 3

    for (int t = 0; t < T_STEPS; ++t) {
        const int cur = t & 1, nxt = cur ^ 1;
        const int pb  = (rb >= 1) ? rb - 1 : 2;        // (t+2) % 3

        // 1) issue W[t+2] and xf32[t+3] (clamped at tail; targets are buffers
        //    whose last reads completed before the previous barrier)
        const int tpw = (t + 2 < T_STEPS) ? t + 2 : T_STEPS - 1;
        const int tpx = (t + 3 < T_STEPS) ? t + 3 : T_STEPS - 1;
        issue_w(tpw, pb);
        issue_xf(tpx, (t + 3) & 3);
        // queue: [W(t+1)x3, xf(t+2), W(t+2)x3, xf(t+3)] = 8

        // 2) fragments from published buffers; x[t+1] fp32 -> bf16 -> xb[nxt]
        //    (xf[t+1] completed at step t-1's wait, published by its barrier;
        //     xb[nxt] is the non-current buffer -> safe to write any time now)
        if (tid < MB * INP) {
            const float xv = *(const float*)((const char*)&xf[(t + 1) & 3][0] + xfoff);
            xb[nxt][xs * XS + xi] = f2bfh(xv);
        }
        const s16x8 a0 = *(const s16x8*)&hb[cur][l * HS + q * 8];
        const s16x8 a1 = *(const s16x8*)&hb[cur][l * HS + 32 + q * 8];
        const s16x8 a2 = *(const s16x8*)&xb[cur][l * XS + q * 8];
        const s16x8 b0 = *(const s16x8*)&Wb[rb][woff];
        const s16x8 b1 = *(const s16x8*)&Wb[rb][woff + 32];
        const s16x8 b2 = *(const s16x8*)&Wb[rb][woff + 64];

        f32x4 z = {0.f, 0.f, 0.f, 0.f};
        f32x4 acc0 = __builtin_amdgcn_mfma_f32_16x16x32_bf16(
                  __builtin_bit_cast(bf16x8, a0), __builtin_bit_cast(bf16x8, b0), z, 0, 0, 0);
        f32x4 acc1 = __builtin_amdgcn_mfma_f32_16x16x32_bf16(
                  __builtin_bit_cast(bf16x8, a1), __builtin_bit_cast(bf16x8, b1), z, 0, 0, 0);
        f32x4 acc2 = __builtin_amdgcn_mfma_f32_16x16x32_bf16(
                  __builtin_bit_cast(bf16x8, a2), __builtin_bit_cast(bf16x8, b2), z, 0, 0, 0);

        // 3) tanh + freeze + h[t+1] writes (VALU overlaps in-flight DMA)
#pragma unroll
        for (int r = 0; r < 4; ++r) {
            const float a  = acc0[r] + acc1[r] + acc2[r];
            const float e  = __expf(2.f * a);
            const float th = 1.f - 2.f * __builtin_amdgcn_rcpf(e + 1.f);
            hc[r] = (t < len4[r]) ? th : hc[r];
            hb[nxt][(q * 4 + r) * HS + colw] = f2bfh(hc[r]);
        }

        // 4) counted wait: completes W(t+1)+xf(t+2) (consumed NEXT step);
        //    W(t+2)/xf(t+3) stay in flight across the barrier. No memory
        //    clobber needed: nothing in THIS iteration reads them, and next
        //    iteration's reads are fenced by the clobbering lgkm asm+barrier.
        asm volatile("s_waitcnt vmcnt(4)");
        asm volatile("s_waitcnt lgkmcnt(0)" ::: "memory");
        __builtin_amdgcn_s_barrier();

        rb = (rb == 2) ? 0 : rb + 1;
    }

    // drain the tail junk prefetches before kernel end
    asm volatile("s_waitcnt vmcnt(0)" ::: "memory");

    // ---- epilogue: out[b] = h_final . W_lin + b_lin  (final h in hb[0]) ----
    const float wl = Wlin[lane];
    const float bl = blin[0];
#pragma unroll
    for (int it = 0; it < 4; ++it) {
        const int s = wv + it * 4;
        float v = bf2f(hb[0][s * HS + lane]) * wl;
#pragma unroll
        for (int off = 32; off > 0; off >>= 1) v += __shfl_down(v, off);
        if (lane == 0) out[bbase + s] = v + bl;
    }
}

extern "C" void kernel_launch(void* const* d_in, const int* in_sizes, int n_in,
                              void* d_out, int out_size, void* d_ws, size_t ws_size,
                              hipStream_t stream) {
    const float* X    = (const float*)d_in[0];      // [B,T,10] fp32
    const int*   L    = (const int*)d_in[1];        // [B] int32
    const float* Wxh  = (const float*)d_in[2];      // [T,10,64]
    const float* Whh  = (const float*)d_in[3];      // [T,64,64]
    const float* Wlin = (const float*)d_in[4];      // [64,1]
    const float* blin = (const float*)d_in[5];      // [1]
    float*       out  = (float*)d_out;              // [B,1] fp32
    short*       Wc   = (short*)d_ws;               // 512*5632 bf16 = 5.77 MB

    prep_w<<<T_STEPS, 256, 0, stream>>>(Wxh, Whh, Wc);
    rnn_main<<<8192 / MB, 256, 0, stream>>>(X, L, Wc, Wlin, blin, out);
}

// Round 3
// 537.208 us; speedup vs baseline: 1.1860x; 1.1860x over previous
//
#include <hip/hip_runtime.h>
#include <stdint.h>

// Problem constants
#define T_STEPS 512
#define HID     64
#define INP     10
#define MB      32          // samples per block (doubled: halves W traffic/sample)
#define NTHR    512         // 8 waves: wave w -> (mt = w>>2, nt = w&3)
#define KS      88          // k-stride (elements) of packed W layout [t][n][KS]
#define HS      72          // h LDS row stride (elems) : 144B, 16B-aligned
#define XS      40          // x LDS row stride (elems) : 80B, 16B-aligned
#define WT_ELEMS (HID*KS)       // 5632 bf16 per step
#define WT_BYTES (WT_ELEMS*2)   // 11264 B per step
#define WS_SLOTS (WT_BYTES/16)  // 704 16B slots

typedef float  f32x4  __attribute__((ext_vector_type(4)));
typedef short  s16x8  __attribute__((ext_vector_type(8)));
typedef __bf16 bf16x8 __attribute__((ext_vector_type(8)));

typedef const __attribute__((address_space(1))) unsigned int* gp_t;
typedef __attribute__((address_space(3))) unsigned int*       lp_t;

__device__ __forceinline__ short f2bf(float f) {          // manual RNE (prep pass)
    unsigned u = __builtin_bit_cast(unsigned, f);
    u = (u + 0x7FFFu + ((u >> 16) & 1u)) >> 16;
    return (short)u;
}
__device__ __forceinline__ short f2bfh(float f) {         // hw cvt (hot loop)
    return __builtin_bit_cast(short, (__bf16)f);
}
__device__ __forceinline__ float bf2f(short s) {
    unsigned u = ((unsigned)(unsigned short)s) << 16;
    return __builtin_bit_cast(float, u);
}

// ---------------------------------------------------------------------------
// Pre-pass: pack [W_hh[t] (64x64) ; W_xh[t] (10x64) ; zeros] transposed into
// bf16 Wc[t][n][k], k-stride 88. LDS stride 65 -> conflict-free transpose.
// ---------------------------------------------------------------------------
__global__ __launch_bounds__(256) void prep_w(const float* __restrict__ Wxh,
                                              const float* __restrict__ Whh,
                                              short* __restrict__ Wc) {
    __shared__ float s_hh[64 * 65];
    __shared__ float s_xh[INP * 65];
    const int t = blockIdx.x, tid = threadIdx.x;
    for (int i = tid; i < 64 * 64; i += 256)
        s_hh[(i >> 6) * 65 + (i & 63)] = Whh[t * 4096 + i];
    for (int i = tid; i < INP * 64; i += 256)
        s_xh[(i >> 6) * 65 + (i & 63)] = Wxh[t * (INP * 64) + i];
    __syncthreads();
    short* dst = Wc + (size_t)t * WT_ELEMS;
    for (int i = tid; i < WT_ELEMS; i += 256) {
        const int n = i / KS, k = i % KS;
        float v = 0.f;
        if (k < 64)      v = s_hh[k * 65 + n];
        else if (k < 74) v = s_xh[(k - 64) * 65 + n];
        dst[i] = f2bf(v);
    }
}

// ---------------------------------------------------------------------------
// Main recurrence. 256 blocks x 512 threads (8 waves), MB=32 samples/block.
// Wave w owns output tile (mt=w>>2, nt=w&3): 3x mfma_f32_16x16x32_bf16/step.
// W double-buffered via global_load_lds; one __syncthreads per step (its
// vmcnt(0)+lgkmcnt(0) drain IS the pipeline sync -- proven-correct r0
// discipline). All global memory issued at the very top of the step so the
// end-of-step drain has ~a full step of slack.
// ---------------------------------------------------------------------------
__global__ __launch_bounds__(NTHR, 2) void rnn_main(const float* __restrict__ X,
                                                    const int* __restrict__ L,
                                                    const short* __restrict__ Wc,
                                                    const float* __restrict__ Wlin,
                                                    const float* __restrict__ blin,
                                                    float* __restrict__ out) {
    __shared__ __attribute__((aligned(16))) short Wb[2][WT_ELEMS + 16];  // 22.6 KB
    __shared__ __attribute__((aligned(16))) short hb[2][MB * HS];        //  9.2 KB
    __shared__ __attribute__((aligned(16))) short xb[2][MB * XS];        //  5.1 KB
    __shared__ int len_s[MB];

    const int tid  = threadIdx.x;
    const int lane = tid & 63;
    const int w    = tid >> 6;        // wave 0..7
    const int mt   = w >> 2;          // M-tile (samples mt*16..mt*16+15)
    const int nt   = w & 3;           // N-tile (hidden cols nt*16..)
    const int q    = lane >> 4;
    const int l    = lane & 15;
    const long long bbase = (long long)blockIdx.x * MB;

    // W DMA: 704 slots over 512 threads (threads 0..191 take a second slot)
    auto issue_w = [&](int tp) {
        const char* src = (const char*)Wc + (size_t)tp * WT_BYTES;
        char* dst = (char*)&Wb[tp & 1][0];
        __builtin_amdgcn_global_load_lds((gp_t)(src + tid * 16),
                                         (lp_t)(dst + tid * 16), 16, 0, 0);
        if (tid < WS_SLOTS - 512)   // 192 threads = waves 0..2 exactly
            __builtin_amdgcn_global_load_lds((gp_t)(src + (tid + 512) * 16),
                                             (lp_t)(dst + (tid + 512) * 16), 16, 0, 0);
    };

    const int xs = tid / INP, xi = tid - (tid / INP) * INP;   // valid tid<320

    // ---- prologue ----------------------------------------------------------
    if (tid < MB) len_s[tid] = L[bbase + tid];
    for (int i = tid; i < MB * HS; i += NTHR) hb[0][i] = 0;
    for (int i = tid; i < MB * XS; i += NTHR) { xb[0][i] = 0; xb[1][i] = 0; }
    if (tid < 16) { Wb[0][WT_ELEMS + tid] = 0; Wb[1][WT_ELEMS + tid] = 0; }
    issue_w(0);
    __syncthreads();                       // zero-fill visible before x[0] store

    float xrA = 0.f, xrB = 0.f;
    if (tid < MB * INP) {
        xb[0][xs * XS + xi] = f2bfh(X[(bbase + xs) * (T_STEPS * INP) + 0 * INP + xi]);
        xrA = X[(bbase + xs) * (T_STEPS * INP) + 1 * INP + xi];   // x[1]
    }
    __syncthreads();                       // drains W[0] DMA + x[0] store

    float hc[4] = {0.f, 0.f, 0.f, 0.f};
    int len4[4];
#pragma unroll
    for (int r = 0; r < 4; ++r) len4[r] = len_s[mt * 16 + q * 4 + r];
    const int colw = nt * 16 + l;
    const int woff = colw * KS + q * 8;
    const int arow = mt * 16 + l;

    auto stepf = [&](int t, float& xr_held, float& xr_new) {
        const int cur = t & 1, nxt = cur ^ 1;

        // ---- top of step: issue ALL global memory (max slack to the drain)
        if (tid < MB * INP && t + 2 < T_STEPS)
            xr_new = X[(bbase + xs) * (T_STEPS * INP) + (long long)(t + 2) * INP + xi];
        if (t + 1 < T_STEPS) issue_w(t + 1);
        // stage x[t+1] (value loaded last step, completed by prev barrier)
        if (tid < MB * INP) xb[nxt][xs * XS + xi] = f2bfh(xr_held);

        // ---- fragments (A rows = this wave's M-tile, B cols = its N-tile)
        const s16x8 a0 = *(const s16x8*)&hb[cur][arow * HS + q * 8];
        const s16x8 a1 = *(const s16x8*)&hb[cur][arow * HS + 32 + q * 8];
        const s16x8 a2 = *(const s16x8*)&xb[cur][arow * XS + q * 8];
        const s16x8 b0 = *(const s16x8*)&Wb[cur][woff];
        const s16x8 b1 = *(const s16x8*)&Wb[cur][woff + 32];
        const s16x8 b2 = *(const s16x8*)&Wb[cur][woff + 64];

        f32x4 z = {0.f, 0.f, 0.f, 0.f};
        f32x4 acc0 = __builtin_amdgcn_mfma_f32_16x16x32_bf16(
                  __builtin_bit_cast(bf16x8, a0), __builtin_bit_cast(bf16x8, b0), z, 0, 0, 0);
        f32x4 acc1 = __builtin_amdgcn_mfma_f32_16x16x32_bf16(
                  __builtin_bit_cast(bf16x8, a1), __builtin_bit_cast(bf16x8, b1), z, 0, 0, 0);
        f32x4 acc2 = __builtin_amdgcn_mfma_f32_16x16x32_bf16(
                  __builtin_bit_cast(bf16x8, a2), __builtin_bit_cast(bf16x8, b2), z, 0, 0, 0);

        // ---- tanh + freeze + h[t+1]
#pragma unroll
        for (int r = 0; r < 4; ++r) {
            const float a  = acc0[r] + acc1[r] + acc2[r];
            const float e  = __expf(2.f * a);
            const float th = 1.f - 2.f * __builtin_amdgcn_rcpf(e + 1.f);
            hc[r] = (t < len4[r]) ? th : hc[r];
            hb[nxt][(mt * 16 + q * 4 + r) * HS + colw] = f2bfh(hc[r]);
        }
        __syncthreads();   // vmcnt(0)+lgkmcnt(0)+barrier: publishes W[t+1], x, h
    };

    for (int tt = 0; tt < T_STEPS; tt += 2) {
        stepf(tt,     xrA, xrB);
        stepf(tt + 1, xrB, xrA);
    }

    // ---- epilogue: out[b] = h_final . W_lin + b_lin  (final h in hb[0]) ----
    const float wl = Wlin[lane];
    const float bl = blin[0];
#pragma unroll
    for (int it = 0; it < 4; ++it) {
        const int s = w + it * 8;
        float v = bf2f(hb[0][s * HS + lane]) * wl;
#pragma unroll
        for (int off = 32; off > 0; off >>= 1) v += __shfl_down(v, off);
        if (lane == 0) out[bbase + s] = v + bl;
    }
}

extern "C" void kernel_launch(void* const* d_in, const int* in_sizes, int n_in,
                              void* d_out, int out_size, void* d_ws, size_t ws_size,
                              hipStream_t stream) {
    const float* X    = (const float*)d_in[0];      // [B,T,10] fp32
    const int*   L    = (const int*)d_in[1];        // [B] int32
    const float* Wxh  = (const float*)d_in[2];      // [T,10,64]
    const float* Whh  = (const float*)d_in[3];      // [T,64,64]
    const float* Wlin = (const float*)d_in[4];      // [64,1]
    const float* blin = (const float*)d_in[5];      // [1]
    float*       out  = (float*)d_out;              // [B,1] fp32
    short*       Wc   = (short*)d_ws;               // 512*5632 bf16 = 5.77 MB

    prep_w<<<T_STEPS, 256, 0, stream>>>(Wxh, Whh, Wc);
    rnn_main<<<8192 / MB, NTHR, 0, stream>>>(X, L, Wc, Wlin, blin, out);
}